// Round 17
// baseline (235.847 us; speedup 1.0000x reference)
//
#include <hip/hip_runtime.h>
#include <stdint.h>

// L2 1-NN, B=4096 x[B,256] vs N=32768 P[N,256] fp32.
// Round 17: (1) screen with 32KB pieces / ring-2 double buffer -> ONE
// VMCNT(0)+barrier per 32 MFMA (halved from R16); loop still has zero VMEM
// besides staging so VMCNT(0) drains a stage issued a full body (~1800cy)
// earlier = free. A-in-LDS + DPP epilogue + LDS key table all kept (R16
// proven, 695 TF). LDS = ring 64K + A 64K + tbl 32K = 160KB.
// (2) rescore two-stage: stage A scans candidate groups from Pb (bf16,
// half traffic) with f32 x (err<=0.31); flag cols with dA <= screen_min+1.5
// (true NN always flagged: E_s+E_A ~ 0.93); stage B exact per-lane fp32 dot
// (proven summation order) for ~1.2 cols/row.
// argmin_j (psq[j] - 2 x.p_j); x_sq drops out. Candidate-group set
// {groupmin <= approx_min + 2.0} provably contains the exact argmin.

#define NB 4096
#define NP 32768
#define ND 256
#define NG 512             // N / 64 column groups
#define MARGIN 2.0f
#define MARGIN_AB 1.5f
#define NSPLIT 8
#define CPB 4096           // cols per split (NP / NSPLIT)

typedef __attribute__((ext_vector_type(8))) __bf16 bf16x8;
typedef __attribute__((ext_vector_type(4))) __bf16 bf16x4;
typedef __attribute__((ext_vector_type(4))) float f32x4;

// ---- workspace layout (bytes) ----
static constexpr size_t OFF_PSQ = 0;                               // 32768 f32
static constexpr size_t OFF_XB  = 131072;                          // 4096x256 bf16
static constexpr size_t OFF_PB  = OFF_XB + (size_t)NB * ND * 2;    // 32768x256 bf16
static constexpr size_t OFF_BM  = OFF_PB + (size_t)NP * ND * 2;    // 4096x512 u32
static constexpr size_t WS_NEED = OFF_BM + (size_t)NB * NG * 4;    // 27,394,048

#define VMCNT(n) asm volatile("s_waitcnt vmcnt(" #n ")" ::: "memory")
#define LGKM(n)  asm volatile("s_waitcnt lgkmcnt(" #n ")" ::: "memory")

__device__ __forceinline__ void gload_lds16(const void* g, void* l) {
    __builtin_amdgcn_global_load_lds(
        (const __attribute__((address_space(1))) uint32_t*)g,
        (__attribute__((address_space(3))) uint32_t*)l, 16, 0, 0);
}
// 16-lane min-reduce on the VALU pipe (DPP); reduce lanes = one DPP row.
__device__ __forceinline__ float dppmin16(float v) {
    int x;
    x = __builtin_amdgcn_update_dpp(0, __float_as_int(v), 0xB1, 0xF, 0xF, true);
    v = fminf(v, __int_as_float(x));   // quad_perm xor1
    x = __builtin_amdgcn_update_dpp(0, __float_as_int(v), 0x4E, 0xF, 0xF, true);
    v = fminf(v, __int_as_float(x));   // quad_perm xor2
    x = __builtin_amdgcn_update_dpp(0, __float_as_int(v), 0x141, 0xF, 0xF, true);
    v = fminf(v, __int_as_float(x));   // row_half_mirror -> min over 8
    x = __builtin_amdgcn_update_dpp(0, __float_as_int(v), 0x140, 0xF, 0xF, true);
    v = fminf(v, __int_as_float(x));   // row_mirror      -> min over 16
    return v;
}
__device__ __forceinline__ unsigned fkey(float f) {
    unsigned u = __float_as_uint(f);
    return (u & 0x80000000u) ? ~u : (u | 0x80000000u);
}
__device__ __forceinline__ float fkey_inv(unsigned u) {
    unsigned o = (u & 0x80000000u) ? (u & 0x7FFFFFFFu) : ~u;
    return __uint_as_float(o);
}
__device__ __forceinline__ unsigned long long umin64(unsigned long long a,
                                                     unsigned long long b) {
    return a < b ? a : b;
}
__device__ __forceinline__ unsigned umin32(unsigned a, unsigned b) {
    return a < b ? a : b;
}

// ------------------------------------------------- prep: bf16 convert + psq
__global__ void prep_kernel(const float* __restrict__ X, const float* __restrict__ P,
                            float* __restrict__ psq, __bf16* __restrict__ Xb,
                            __bf16* __restrict__ Pb) {
    int row  = blockIdx.x * 4 + (threadIdx.x >> 6);  // one wave per row
    int lane = threadIdx.x & 63;
    if (row < NP) {
        f32x4 v = ((const f32x4*)(P + (size_t)row * ND))[lane];
        bf16x4 b;
        b.x = (__bf16)v.x; b.y = (__bf16)v.y; b.z = (__bf16)v.z; b.w = (__bf16)v.w;
        ((bf16x4*)(Pb + (size_t)row * ND))[lane] = b;
        float s = v.x*v.x + v.y*v.y + v.z*v.z + v.w*v.w;
        #pragma unroll
        for (int off = 32; off > 0; off >>= 1) s += __shfl_down(s, off);
        if (lane == 0) psq[row] = s;
    } else {
        int r = row - NP;   // < NB
        f32x4 v = ((const f32x4*)(X + (size_t)r * ND))[lane];
        bf16x4 b;
        b.x = (__bf16)v.x; b.y = (__bf16)v.y; b.z = (__bf16)v.z; b.w = (__bf16)v.w;
        ((bf16x4*)(Xb + (size_t)r * ND))[lane] = b;
    }
}

// ---------- A-in-LDS N-sweep screen, 32KB dbuf pieces, DPP epilogue ---------
// Grid 256 = 32 mblk x 8 split (bid&7 -> XCD-local 2MB B-panel); 1 block/CU.
// 512 thr = 8 waves (wm 0..1 x wn 0..3); wave tile 64 rows x 64 cols,
// acc[4][4]. Sweep: 64 bodies (body b: n-tile b>>2, k-slabs (b&3)*2, +1;
// piece = 256 cols x 64 k = 32KB). Ring 2 x 32KB, slot b&1.
// Body b: VMCNT(0) [stage(b) complete - issued a full body earlier];
// s_barrier [publishes slot b for ALL waves]; stage(b+1) [WAR: slot (b+1)&1's
// readers lgkm-retired before their MFMA in body b-1, which precedes
// barrier(b)]; qq==0: prefetch cq; read av0/bv0/av1/bv1; 16 MFMA slab0;
// 16 MFMA slab1; qq==3: DPP epilogue -> LDS tbl (no VMEM). Flush tbl once.
__global__ __launch_bounds__(512, 2)
void nn_db_kernel(const __bf16* __restrict__ Xb, const __bf16* __restrict__ Pb,
                  const float* __restrict__ psq,
                  unsigned* __restrict__ blockmin) {
    __shared__ __align__(16) char smem[163840];
    char* ring  = smem;                                   // 2 x 32KB
    char* A_lds = smem + 65536;                           // 64KB
    unsigned (*tbl)[64] = (unsigned (*)[64])(smem + 131072);  // 128x64 u32

    const int tid  = threadIdx.x;
    const int lane = tid & 63;
    const int wave = tid >> 6;
    const int wm = wave >> 2, wn = wave & 3;
    const int bid    = blockIdx.x;
    const int nsplit = bid & 7;
    const int mblk   = bid >> 3;
    const int bm     = mblk * 128;
    const int Nb     = nsplit * CPB;
    const int fr = lane & 15, kg = lane >> 4;
    const int wbase16 = (tid & ~63) * 16;

    f32x4 acc[4][4];
    #pragma unroll
    for (int i = 0; i < 4; ++i)
        #pragma unroll
        for (int j = 0; j < 4; ++j) acc[i][j] = (f32x4){0.f, 0.f, 0.f, 0.f};

    auto stage = [&](int p) {                  // p = body 0..63, 32KB piece
        char* dst = ring + (size_t)(p & 1) * 32768;
        const int colb = Nb + (p >> 2) * 256;
        const int kq0  = (p & 3) * 2;
        #pragma unroll
        for (int s = 0; s < 2; ++s)
            #pragma unroll
            for (int i = 0; i < 2; ++i) {
                const int c = i * 512 + tid;   // chunk 0..1023 within slab
                const int fn = c >> 6;
                const int l  = c & 63;
                gload_lds16(Pb + (size_t)(colb + fn * 16 + (l & 15)) * ND +
                                (kq0 + s) * 32 + (l >> 4) * 8,
                            dst + s * 16384 + i * 8192 + wbase16);
            }
    };

    // ---- prologue: A (8 issues) + piece 0 ----
    #pragma unroll
    for (int i = 0; i < 8; ++i) {
        const int c  = i * 512 + tid;              // chunk 0..4095
        const int q  = c >> 9;                     // k-slab 0..7
        const int fm = (c >> 6) & 7;               // 16-row frag 0..7
        const int l  = c & 63;
        gload_lds16(Xb + (size_t)(bm + fm * 16 + (l & 15)) * ND +
                        q * 32 + (l >> 4) * 8,
                    A_lds + (size_t)(i * 512) * 16 + wbase16);
    }
    stage(0);

    #pragma unroll 1
    for (int nt = 0; nt < 16; ++nt) {
        float cq[4];
        #pragma unroll
        for (int qq = 0; qq < 4; ++qq) {
            const int b = nt * 4 + qq;
            VMCNT(0);                          // stage(b) complete (lead=1 body)
            __builtin_amdgcn_s_barrier();      // slot b published for ALL waves
            __builtin_amdgcn_sched_barrier(0);
            if (b < 63) stage(b + 1);
            if (qq == 0) {
                const int colb = Nb + nt * 256 + wn * 64;
                #pragma unroll
                for (int ni = 0; ni < 4; ++ni)
                    cq[ni] = psq[colb + ni * 16 + fr];   // used at qq==3
            }
            const char* slot = ring + (size_t)(b & 1) * 32768;
            const int qa = (b & 3) * 2;        // first k-slab of this body
            bf16x8 av0[4], bv0[4], av1[4], bv1[4];
            #pragma unroll
            for (int mi = 0; mi < 4; ++mi)
                av0[mi] = *(const bf16x8*)(A_lds +
                    (size_t)((qa * 8 + wm * 4 + mi) * 64 + lane) * 16);
            #pragma unroll
            for (int ni = 0; ni < 4; ++ni)
                bv0[ni] = *(const bf16x8*)(slot +
                    (size_t)((wn * 4 + ni) * 64 + lane) * 16);
            #pragma unroll
            for (int mi = 0; mi < 4; ++mi)
                av1[mi] = *(const bf16x8*)(A_lds +
                    (size_t)(((qa + 1) * 8 + wm * 4 + mi) * 64 + lane) * 16);
            #pragma unroll
            for (int ni = 0; ni < 4; ++ni)
                bv1[ni] = *(const bf16x8*)(slot + 16384 +
                    (size_t)((wn * 4 + ni) * 64 + lane) * 16);
            __builtin_amdgcn_s_setprio(1);
            #pragma unroll
            for (int mi = 0; mi < 4; ++mi)
                #pragma unroll
                for (int ni = 0; ni < 4; ++ni)
                    acc[mi][ni] = __builtin_amdgcn_mfma_f32_16x16x32_bf16(
                        av0[mi], bv0[ni], acc[mi][ni], 0, 0, 0);
            #pragma unroll
            for (int mi = 0; mi < 4; ++mi)
                #pragma unroll
                for (int ni = 0; ni < 4; ++ni)
                    acc[mi][ni] = __builtin_amdgcn_mfma_f32_16x16x32_bf16(
                        av1[mi], bv1[ni], acc[mi][ni], 0, 0, 0);
            __builtin_amdgcn_s_setprio(0);

            if (qq == 3) {
                // ---- epilogue: VALU-only reduce -> LDS key table ----
                const int g = nt * 4 + wn;
                #pragma unroll
                for (int mi = 0; mi < 4; ++mi) {
                    #pragma unroll
                    for (int r = 0; r < 4; ++r) {
                        float d = fmaf(-2.f, acc[mi][0][r], cq[0]);
                        #pragma unroll
                        for (int ni = 1; ni < 4; ++ni)
                            d = fminf(d, fmaf(-2.f, acc[mi][ni][r], cq[ni]));
                        d = dppmin16(d);
                        if (fr == 0)
                            tbl[wm * 64 + mi * 16 + kg * 4 + r][g] = fkey(d);
                    }
                }
                #pragma unroll
                for (int i = 0; i < 4; ++i)
                    #pragma unroll
                    for (int j = 0; j < 4; ++j)
                        acc[i][j] = (f32x4){0.f, 0.f, 0.f, 0.f};
            }
        }
    }

    // ---- flush key table: 8192 u32, coalesced ----
    __syncthreads();
    #pragma unroll
    for (int i = 0; i < 8; ++i) {
        const int f2  = i * 512 + tid;             // uint2 index
        uint2 v = ((const uint2*)tbl)[f2];
        const int idx = f2 * 2;
        const int row = idx >> 6, col = idx & 63;
        *(uint2*)&blockmin[(size_t)(bm + row) * NG + nsplit * 64 + col] = v;
    }
}

// -------- rescore: wave-per-row, two-stage (bf16 scan -> fp32 exact) --------
__global__ __launch_bounds__(512, 2)
void rescore2_kernel(const float* __restrict__ X, const float* __restrict__ P,
                     const __bf16* __restrict__ Pb,
                     const float* __restrict__ psq,
                     const unsigned* __restrict__ blockmin,
                     float* __restrict__ out) {
    __shared__ float Xs[8][256];
    __shared__ unsigned short wcand[8][512];
    __shared__ int wcnt[8];

    const int tid = threadIdx.x, lane = tid & 63, wv = tid >> 6;
    const int row = blockIdx.x * 8 + wv;

    ((f32x4*)Xs[wv])[lane] = ((const f32x4*)(X + (size_t)row * ND))[lane];
    if (lane == 0) wcnt[wv] = 0;

    const unsigned* bmr = blockmin + (size_t)row * NG;
    uint4 ka = ((const uint4*)bmr)[lane * 2];
    uint4 kb = ((const uint4*)bmr)[lane * 2 + 1];
    unsigned km = umin32(umin32(umin32(ka.x, ka.y), umin32(ka.z, ka.w)),
                         umin32(umin32(kb.x, kb.y), umin32(kb.z, kb.w)));
    #pragma unroll
    for (int m = 1; m < 64; m <<= 1) km = umin32(km, __shfl_xor(km, m));
    const float mval = fkey_inv(km);
    const unsigned thr = fkey(mval + MARGIN);       // group filter
    const float dthr = mval + MARGIN_AB;            // stage-A column filter

    const unsigned k8[8] = {ka.x, ka.y, ka.z, ka.w, kb.x, kb.y, kb.z, kb.w};
    #pragma unroll
    for (int i = 0; i < 8; ++i)
        if (k8[i] <= thr)
            wcand[wv][atomicAdd(&wcnt[wv], 1)] = (unsigned short)(lane * 8 + i);
    LGKM(0);                             // same-wave DS ops complete, in order
    const int n = wcnt[wv];

    unsigned long long best = 0xFFFFFFFFFFFFFFFFull;
    const f32x4* x4 = (const f32x4*)Xs[wv];
    for (int c = 0; c < n; ++c) {
        const int col = (int)wcand[wv][c] * 64 + lane;
        // ---- stage A: bf16 P row x f32 x (error <= ~0.31) ----
        const bf16x8* pr = (const bf16x8*)(Pb + (size_t)col * ND);
        float s = 0.f;
        #pragma unroll
        for (int i = 0; i < 32; ++i) {
            bf16x8 v = pr[i];
            f32x4 xa = x4[i * 2], xb = x4[i * 2 + 1];
            s = fmaf(xa.x, (float)v[0], s); s = fmaf(xa.y, (float)v[1], s);
            s = fmaf(xa.z, (float)v[2], s); s = fmaf(xa.w, (float)v[3], s);
            s = fmaf(xb.x, (float)v[4], s); s = fmaf(xb.y, (float)v[5], s);
            s = fmaf(xb.z, (float)v[6], s); s = fmaf(xb.w, (float)v[7], s);
        }
        float dA = fmaf(-2.f, s, psq[col]);
        if (dA <= dthr) {
            // ---- stage B: exact fp32 (same summation order as r8-r16) ----
            const f32x4* p4 = (const f32x4*)(P + (size_t)col * ND);
            float se = 0.f;
            #pragma unroll 16
            for (int i = 0; i < 64; ++i) {
                f32x4 pv = p4[i], xv = x4[i];
                se = fmaf(xv.x, pv.x, se); se = fmaf(xv.y, pv.y, se);
                se = fmaf(xv.z, pv.z, se); se = fmaf(xv.w, pv.w, se);
            }
            float d = fmaf(-2.f, se, psq[col]);
            best = umin64(best, ((unsigned long long)fkey(d) << 32) |
                                (unsigned long long)(unsigned)col);
        }
    }
    #pragma unroll
    for (int m = 1; m < 64; m <<= 1)
        best = umin64(best, __shfl_xor(best, m));
    const unsigned bc = (unsigned)(best & 0xFFFFFFFFull);
    ((f32x4*)(out + (size_t)row * ND))[lane] =
        ((const f32x4*)(P + (size_t)bc * ND))[lane];
}

// ======================= fallback: exact fp32 path (small ws) ===============
#define BM1 128
#define BN1 128
#define BK1 32
#define LDA1 132

__global__ void psq_init_kernel(const float* __restrict__ P, float* __restrict__ psq,
                                unsigned long long* __restrict__ minpack) {
    int row  = blockIdx.x * 4 + (threadIdx.x >> 6);
    int lane = threadIdx.x & 63;
    float4 p4 = ((const float4*)(P + (size_t)row * ND))[lane];
    float s = p4.x*p4.x + p4.y*p4.y + p4.z*p4.z + p4.w*p4.w;
    #pragma unroll
    for (int off = 32; off > 0; off >>= 1) s += __shfl_down(s, off);
    if (lane == 0) psq[row] = s;
    int gid = blockIdx.x * blockDim.x + threadIdx.x;
    if (gid < NB) minpack[gid] = 0xFFFFFFFFFFFFFFFFull;
}

__global__ __launch_bounds__(256, 2)
void nn_main_kernel(const float* __restrict__ X, const float* __restrict__ P,
                    const float* __restrict__ psq,
                    unsigned long long* __restrict__ minpack) {
    __shared__ __align__(16) char smem_raw[2 * BK1 * LDA1 * 4];
    float (*As)[LDA1] = (float (*)[LDA1])smem_raw;
    float (*Bs)[LDA1] = (float (*)[LDA1])(smem_raw + BK1 * LDA1 * 4);
    const int bm  = blockIdx.y * BM1;
    const int bn  = blockIdx.x * BN1;
    const int tid = threadIdx.x;
    const int tx  = tid & 15;
    const int ty  = tid >> 4;
    float acc[8][8];
    #pragma unroll
    for (int i = 0; i < 8; ++i)
        #pragma unroll
        for (int j = 0; j < 8; ++j) acc[i][j] = 0.f;
    const int lrow = tid >> 3;
    const int lk   = (tid & 7) * 4;
    for (int k0 = 0; k0 < ND; k0 += BK1) {
        #pragma unroll
        for (int p = 0; p < 4; ++p) {
            int r = p * 32 + lrow;
            float4 aa = *(const float4*)(X + (size_t)(bm + r) * ND + k0 + lk);
            As[lk+0][r] = aa.x; As[lk+1][r] = aa.y; As[lk+2][r] = aa.z; As[lk+3][r] = aa.w;
            float4 bb = *(const float4*)(P + (size_t)(bn + r) * ND + k0 + lk);
            Bs[lk+0][r] = bb.x; Bs[lk+1][r] = bb.y; Bs[lk+2][r] = bb.z; Bs[lk+3][r] = bb.w;
        }
        __syncthreads();
        #pragma unroll 4
        for (int k = 0; k < BK1; ++k) {
            float4 a0 = *(const float4*)&As[k][ty*8];
            float4 a1 = *(const float4*)&As[k][ty*8 + 4];
            float4 b0 = *(const float4*)&Bs[k][tx*4];
            float4 b1 = *(const float4*)&Bs[k][64 + tx*4];
            float av2[8] = {a0.x,a0.y,a0.z,a0.w,a1.x,a1.y,a1.z,a1.w};
            float bv2[8] = {b0.x,b0.y,b0.z,b0.w,b1.x,b1.y,b1.z,b1.w};
            #pragma unroll
            for (int i = 0; i < 8; ++i)
                #pragma unroll
                for (int j = 0; j < 8; ++j)
                    acc[i][j] = fmaf(av2[i], bv2[j], acc[i][j]);
        }
        __syncthreads();
    }
    unsigned long long (*red)[16] = (unsigned long long (*)[16])smem_raw;
    float cj[8];
    int   jglob[8];
    #pragma unroll
    for (int j = 0; j < 8; ++j) {
        int c = (j < 4) ? (tx*4 + j) : (64 + tx*4 + (j - 4));
        jglob[j] = bn + c;
        cj[j]    = psq[bn + c];
    }
    #pragma unroll
    for (int i = 0; i < 8; ++i) {
        float bestv = 0.f; unsigned bidx = 0u; bool first = true;
        #pragma unroll
        for (int j = 0; j < 8; ++j) {
            float s = fmaf(-2.f, acc[i][j], cj[j]);
            if (first || s < bestv) { bestv = s; bidx = (unsigned)jglob[j]; first = false; }
        }
        unsigned u = fkey(bestv);
        red[ty*8 + i][tx] = ((unsigned long long)u << 32) | (unsigned long long)bidx;
    }
    __syncthreads();
    if (tid < BM1) {
        unsigned long long m = red[tid][0];
        #pragma unroll
        for (int t = 1; t < 16; ++t) m = umin64(m, red[tid][t]);
        atomicMin(&minpack[bm + tid], m);
    }
}

__global__ void gather_kernel(const float* __restrict__ P,
                              const unsigned long long* __restrict__ minpack,
                              float* __restrict__ out) {
    int row = blockIdx.x;
    unsigned idx = (unsigned)(minpack[row] & 0xFFFFFFFFull);
    int lane = threadIdx.x;
    ((float4*)(out + (size_t)row * ND))[lane] =
        ((const float4*)(P + (size_t)idx * ND))[lane];
}

// ------------------------------------------------------------------- launch
extern "C" void kernel_launch(void* const* d_in, const int* in_sizes, int n_in,
                              void* d_out, int out_size, void* d_ws, size_t ws_size,
                              hipStream_t stream) {
    const float* X = (const float*)d_in[0];
    const float* P = (const float*)d_in[1];
    float* out = (float*)d_out;
    char* w = (char*)d_ws;

    if (ws_size >= WS_NEED) {
        float* psq = (float*)(w + OFF_PSQ);
        __bf16* Xb = (__bf16*)(w + OFF_XB);
        __bf16* Pb = (__bf16*)(w + OFF_PB);
        unsigned* blockmin = (unsigned*)(w + OFF_BM);

        prep_kernel<<<(NP + NB) / 4, 256, 0, stream>>>(X, P, psq, Xb, Pb);
        nn_db_kernel<<<(NB / 128) * NSPLIT, 512, 0, stream>>>(Xb, Pb, psq,
                                                              blockmin);
        rescore2_kernel<<<NB / 8, 512, 0, stream>>>(X, P, Pb, psq, blockmin,
                                                    out);
    } else {
        float* psq = (float*)w;
        unsigned long long* minpack = (unsigned long long*)(w + (size_t)NP * 4);
        psq_init_kernel<<<NP / 4, 256, 0, stream>>>(P, psq, minpack);
        dim3 grid(NP / BN1, NB / BM1);
        nn_main_kernel<<<grid, dim3(256), 0, stream>>>(X, P, psq, minpack);
        gather_kernel<<<NB, 64, 0, stream>>>(P, minpack, out);
    }
}

// Round 18
// 204.944 us; speedup vs baseline: 1.1508x; 1.1508x over previous
//
#include <hip/hip_runtime.h>
#include <stdint.h>

// L2 1-NN, B=4096 x[B,256] vs N=32768 P[N,256] fp32.
// Round 18: R16 screen byte-identical (98.8us, 695 TF, class plateau) +
// load-BALANCED rescore. R17 showed rescore is latency/imbalance-bound
// (Occ 12%, VALU 6%): a few rows with many candidate groups serialize.
// New: cand_kernel emits a global (row,group) pair list (lives in the dead
// Xb region; ctr zeroed via hipMemsetAsync - graph-legal); rescore_bal runs
// 4096 persistent waves striding the pair list -- uniform work/wave, quad-
// per-column coalesced reads (4x fewer cache transactions), one u64
// atomicMin per pair into minpack; gather from minpack.
// argmin_j (psq[j] - 2 x.p_j); x_sq drops out. Candidate-group set
// {groupmin <= approx_min + 2.0} provably contains the exact argmin.

#define NB 4096
#define NP 32768
#define ND 256
#define NG 512             // N / 64 column groups
#define MARGIN 2.0f
#define NSPLIT 8
#define CPB 4096           // cols per split (NP / NSPLIT)
#define PAIR_CAP 500000

typedef __attribute__((ext_vector_type(8))) __bf16 bf16x8;
typedef __attribute__((ext_vector_type(4))) __bf16 bf16x4;
typedef __attribute__((ext_vector_type(4))) float f32x4;

// ---- workspace layout (bytes) ----
static constexpr size_t OFF_PSQ = 0;                               // 32768 f32
static constexpr size_t OFF_XB  = 131072;                          // 4096x256 bf16
static constexpr size_t OFF_PB  = OFF_XB + (size_t)NB * ND * 2;    // 32768x256 bf16
static constexpr size_t OFF_BM  = OFF_PB + (size_t)NP * ND * 2;    // 4096x512 u32
static constexpr size_t WS_NEED = OFF_BM + (size_t)NB * NG * 4;    // 27,394,048
// Reuse of the dead Xb region after the screen (Xb read only by screen):
static constexpr size_t OFF_MP    = OFF_XB;                        // 4096 u64
static constexpr size_t OFF_CTR   = OFF_XB + 32768;                // 1 u32 (+pad)
static constexpr size_t OFF_PAIRS = OFF_XB + 32832;                // <=500K u32

#define VMCNT(n) asm volatile("s_waitcnt vmcnt(" #n ")" ::: "memory")
#define LGKM(n)  asm volatile("s_waitcnt lgkmcnt(" #n ")" ::: "memory")

__device__ __forceinline__ void gload_lds16(const void* g, void* l) {
    __builtin_amdgcn_global_load_lds(
        (const __attribute__((address_space(1))) uint32_t*)g,
        (__attribute__((address_space(3))) uint32_t*)l, 16, 0, 0);
}
// 16-lane min-reduce on the VALU pipe (DPP); reduce lanes = one DPP row.
__device__ __forceinline__ float dppmin16(float v) {
    int x;
    x = __builtin_amdgcn_update_dpp(0, __float_as_int(v), 0xB1, 0xF, 0xF, true);
    v = fminf(v, __int_as_float(x));   // quad_perm xor1
    x = __builtin_amdgcn_update_dpp(0, __float_as_int(v), 0x4E, 0xF, 0xF, true);
    v = fminf(v, __int_as_float(x));   // quad_perm xor2
    x = __builtin_amdgcn_update_dpp(0, __float_as_int(v), 0x141, 0xF, 0xF, true);
    v = fminf(v, __int_as_float(x));   // row_half_mirror -> min over 8
    x = __builtin_amdgcn_update_dpp(0, __float_as_int(v), 0x140, 0xF, 0xF, true);
    v = fminf(v, __int_as_float(x));   // row_mirror      -> min over 16
    return v;
}
__device__ __forceinline__ unsigned fkey(float f) {
    unsigned u = __float_as_uint(f);
    return (u & 0x80000000u) ? ~u : (u | 0x80000000u);
}
__device__ __forceinline__ float fkey_inv(unsigned u) {
    unsigned o = (u & 0x80000000u) ? (u & 0x7FFFFFFFu) : ~u;
    return __uint_as_float(o);
}
__device__ __forceinline__ unsigned long long umin64(unsigned long long a,
                                                     unsigned long long b) {
    return a < b ? a : b;
}
__device__ __forceinline__ unsigned umin32(unsigned a, unsigned b) {
    return a < b ? a : b;
}

// ------------------------------------------------- prep: bf16 convert + psq
__global__ void prep_kernel(const float* __restrict__ X, const float* __restrict__ P,
                            float* __restrict__ psq, __bf16* __restrict__ Xb,
                            __bf16* __restrict__ Pb) {
    int row  = blockIdx.x * 4 + (threadIdx.x >> 6);  // one wave per row
    int lane = threadIdx.x & 63;
    if (row < NP) {
        f32x4 v = ((const f32x4*)(P + (size_t)row * ND))[lane];
        bf16x4 b;
        b.x = (__bf16)v.x; b.y = (__bf16)v.y; b.z = (__bf16)v.z; b.w = (__bf16)v.w;
        ((bf16x4*)(Pb + (size_t)row * ND))[lane] = b;
        float s = v.x*v.x + v.y*v.y + v.z*v.z + v.w*v.w;
        #pragma unroll
        for (int off = 32; off > 0; off >>= 1) s += __shfl_down(s, off);
        if (lane == 0) psq[row] = s;
    } else {
        int r = row - NP;   // < NB
        f32x4 v = ((const f32x4*)(X + (size_t)r * ND))[lane];
        bf16x4 b;
        b.x = (__bf16)v.x; b.y = (__bf16)v.y; b.z = (__bf16)v.z; b.w = (__bf16)v.w;
        ((bf16x4*)(Xb + (size_t)r * ND))[lane] = b;
    }
}

// ------------- A-in-LDS N-sweep screen (R16, byte-identical: 98.8us) --------
__global__ __launch_bounds__(512, 2)
void nn_dpp_kernel(const __bf16* __restrict__ Xb, const __bf16* __restrict__ Pb,
                   const float* __restrict__ psq,
                   unsigned* __restrict__ blockmin) {
    __shared__ __align__(16) char smem[163840];
    char* ring  = smem;                                   // 4 x 16KB
    char* A_lds = smem + 65536;                           // 64KB
    unsigned (*tbl)[64] = (unsigned (*)[64])(smem + 131072);  // 128x64 u32

    const int tid  = threadIdx.x;
    const int lane = tid & 63;
    const int wave = tid >> 6;
    const int wm = wave >> 2, wn = wave & 3;
    const int bid    = blockIdx.x;
    const int nsplit = bid & 7;
    const int mblk   = bid >> 3;
    const int bm     = mblk * 128;
    const int Nb     = nsplit * CPB;
    const int fr = lane & 15, kg = lane >> 4;
    const int wbase16 = (tid & ~63) * 16;

    f32x4 acc[4][4];
    #pragma unroll
    for (int i = 0; i < 4; ++i)
        #pragma unroll
        for (int j = 0; j < 4; ++j) acc[i][j] = (f32x4){0.f, 0.f, 0.f, 0.f};

    auto stage = [&](int p) {
        char* dst = ring + (size_t)(p & 3) * 16384;
        const int colb = Nb + (p >> 3) * 256;
        const int kq   = p & 7;
        #pragma unroll
        for (int i = 0; i < 2; ++i) {
            const int c = i * 512 + tid;          // chunk 0..1023
            const int fn = c >> 6;
            const int l  = c & 63;
            gload_lds16(Pb + (size_t)(colb + fn * 16 + (l & 15)) * ND +
                            kq * 32 + (l >> 4) * 8,
                        dst + i * 8192 + wbase16);
        }
    };

    // ---- prologue: A (8 issues) + pieces 0..2 ----
    #pragma unroll
    for (int i = 0; i < 8; ++i) {
        const int c  = i * 512 + tid;              // chunk 0..4095
        const int q  = c >> 9;                     // k-slab 0..7
        const int fm = (c >> 6) & 7;               // 16-row frag 0..7
        const int l  = c & 63;
        gload_lds16(Xb + (size_t)(bm + fm * 16 + (l & 15)) * ND +
                        q * 32 + (l >> 4) * 8,
                    A_lds + (size_t)(i * 512) * 16 + wbase16);
    }
    stage(0); stage(1); stage(2);
    VMCNT(4);                                  // A(8)+s0 drained; s1,s2 fly
    __builtin_amdgcn_s_barrier();              // A + slot0 published
    __builtin_amdgcn_sched_barrier(0);

    bf16x8 av[2][4], bv[2][4];
    #pragma unroll
    for (int mi = 0; mi < 4; ++mi)
        av[0][mi] = *(const bf16x8*)(A_lds +
            (size_t)((wm * 4 + mi) * 64 + lane) * 16);
    #pragma unroll
    for (int ni = 0; ni < 4; ++ni)
        bv[0][ni] = *(const bf16x8*)(ring +
            (size_t)((wn * 4 + ni) * 64 + lane) * 16);

    #pragma unroll 1
    for (int nt = 0; nt < 16; ++nt) {
        float cq[4];
        #pragma unroll
        for (int q = 0; q < 8; ++q) {
            const int t = nt * 8 + q;
            const int cur = q & 1, nxt = cur ^ 1;
            if (t >= 126)            { VMCNT(0); }
            else if (q == 1 || q == 2) { VMCNT(6); }
            else                     { VMCNT(2); }
            __builtin_amdgcn_s_barrier();      // ALL waves' stage(t+1) done
            __builtin_amdgcn_sched_barrier(0);
            if (t < 127) {
                const int qn = (q + 1) & 7;
                #pragma unroll
                for (int mi = 0; mi < 4; ++mi)
                    av[nxt][mi] = *(const bf16x8*)(A_lds +
                        (size_t)((qn * 8 + wm * 4 + mi) * 64 + lane) * 16);
                const char* pc = ring + (size_t)((t + 1) & 3) * 16384;
                #pragma unroll
                for (int ni = 0; ni < 4; ++ni)
                    bv[nxt][ni] = *(const bf16x8*)(pc +
                        (size_t)((wn * 4 + ni) * 64 + lane) * 16);
            }
            if (t <= 124) stage(t + 3);
            if (q == 0) {
                const int colb = Nb + nt * 256 + wn * 64;
                #pragma unroll
                for (int ni = 0; ni < 4; ++ni)
                    cq[ni] = psq[colb + ni * 16 + fr];   // drains by q==3
            }
            __builtin_amdgcn_s_setprio(1);
            #pragma unroll
            for (int mi = 0; mi < 4; ++mi)
                #pragma unroll
                for (int ni = 0; ni < 4; ++ni)
                    acc[mi][ni] = __builtin_amdgcn_mfma_f32_16x16x32_bf16(
                        av[cur][mi], bv[cur][ni], acc[mi][ni], 0, 0, 0);
            __builtin_amdgcn_s_setprio(0);

            if (q == 7) {
                // ---- epilogue: VALU-only reduce -> LDS key table ----
                const int g = nt * 4 + wn;
                #pragma unroll
                for (int mi = 0; mi < 4; ++mi) {
                    #pragma unroll
                    for (int r = 0; r < 4; ++r) {
                        float d = fmaf(-2.f, acc[mi][0][r], cq[0]);
                        #pragma unroll
                        for (int ni = 1; ni < 4; ++ni)
                            d = fminf(d, fmaf(-2.f, acc[mi][ni][r], cq[ni]));
                        d = dppmin16(d);
                        if (fr == 0)
                            tbl[wm * 64 + mi * 16 + kg * 4 + r][g] = fkey(d);
                    }
                }
                #pragma unroll
                for (int i = 0; i < 4; ++i)
                    #pragma unroll
                    for (int j = 0; j < 4; ++j)
                        acc[i][j] = (f32x4){0.f, 0.f, 0.f, 0.f};
            }
        }
    }

    // ---- flush key table: 8192 u32, coalesced ----
    __syncthreads();
    #pragma unroll
    for (int i = 0; i < 8; ++i) {
        const int f2  = i * 512 + tid;             // uint2 index
        uint2 v = ((const uint2*)tbl)[f2];
        const int idx = f2 * 2;
        const int row = idx >> 6, col = idx & 63;
        *(uint2*)&blockmin[(size_t)(bm + row) * NG + nsplit * 64 + col] = v;
    }
}

// ---------- candidate build: wave per row -> global (row,group) pairs -------
__global__ __launch_bounds__(512, 2)
void cand_kernel(const unsigned* __restrict__ blockmin,
                 unsigned* __restrict__ pairs, unsigned* __restrict__ ctr,
                 unsigned long long* __restrict__ minpack) {
    const int tid = threadIdx.x, lane = tid & 63, wv = tid >> 6;
    const int row = blockIdx.x * 8 + wv;

    const unsigned* bmr = blockmin + (size_t)row * NG;
    uint4 ka = ((const uint4*)bmr)[lane * 2];
    uint4 kb = ((const uint4*)bmr)[lane * 2 + 1];
    unsigned km = umin32(umin32(umin32(ka.x, ka.y), umin32(ka.z, ka.w)),
                         umin32(umin32(kb.x, kb.y), umin32(kb.z, kb.w)));
    #pragma unroll
    for (int m = 1; m < 64; m <<= 1) km = umin32(km, __shfl_xor(km, m));
    const unsigned thr = fkey(fkey_inv(km) + MARGIN);

    if (lane == 0) minpack[row] = 0xFFFFFFFFFFFFFFFFull;

    const unsigned k8[8] = {ka.x, ka.y, ka.z, ka.w, kb.x, kb.y, kb.z, kb.w};
    #pragma unroll
    for (int i = 0; i < 8; ++i)
        if (k8[i] <= thr) {
            unsigned pos = atomicAdd(ctr, 1u);
            if (pos < PAIR_CAP)
                pairs[pos] = ((unsigned)row << 9) | (unsigned)(lane * 8 + i);
        }
}

// ------- balanced rescore: persistent waves stride the pair list ------------
// 1024 blocks x 256 thr = 4096 waves; pair = one (row, 64-col group).
// Quad-per-column layout: lane l -> col = g*64 + cc*16 + (l>>2), reads
// f32x4 index (l&3)+4i (quads cover consecutive 64B); quad-sum via 2
// shfl_xor; per-wave u64 key min; ONE atomicMin per pair.
__global__ __launch_bounds__(256, 4)
void rescore_bal_kernel(const float* __restrict__ X, const float* __restrict__ P,
                        const float* __restrict__ psq,
                        const unsigned* __restrict__ pairs,
                        const unsigned* __restrict__ ctr,
                        unsigned long long* __restrict__ minpack) {
    const int lane = threadIdx.x & 63;
    const int gw   = blockIdx.x * 4 + (threadIdx.x >> 6);
    const int npairs = (int)umin32(*ctr, PAIR_CAP);

    for (int idx = gw; idx < npairs; idx += 4096) {
        const unsigned pr = pairs[idx];
        const int row = (int)(pr >> 9);
        const int g   = (int)(pr & 511u);

        // load this row's x, strided quarter per lane (quad covers full row)
        const f32x4* x4 = (const f32x4*)(X + (size_t)row * ND);
        f32x4 xr[16];
        #pragma unroll
        for (int i = 0; i < 16; ++i) xr[i] = x4[(lane & 3) + i * 4];

        unsigned long long best = 0xFFFFFFFFFFFFFFFFull;
        #pragma unroll
        for (int cc = 0; cc < 4; ++cc) {
            const int col = g * 64 + cc * 16 + (lane >> 2);
            const f32x4* p4 = (const f32x4*)(P + (size_t)col * ND);
            float s = 0.f;
            #pragma unroll
            for (int i = 0; i < 16; ++i) {
                f32x4 pv = p4[(lane & 3) + i * 4], xv = xr[i];
                s = fmaf(xv.x, pv.x, s); s = fmaf(xv.y, pv.y, s);
                s = fmaf(xv.z, pv.z, s); s = fmaf(xv.w, pv.w, s);
            }
            s += __shfl_xor(s, 1);
            s += __shfl_xor(s, 2);          // full quad sum on all 4 lanes
            unsigned long long key = 0xFFFFFFFFFFFFFFFFull;
            if ((lane & 3) == 0) {
                float d = fmaf(-2.f, s, psq[col]);
                key = ((unsigned long long)fkey(d) << 32) |
                      (unsigned long long)(unsigned)col;
            }
            best = umin64(best, key);
        }
        #pragma unroll
        for (int m = 1; m < 64; m <<= 1)
            best = umin64(best, __shfl_xor(best, m));
        if (lane == 0) atomicMin(&minpack[row], best);
    }
}

// ------------------------------------------------------------------- gather
__global__ void gather_kernel(const float* __restrict__ P,
                              const unsigned long long* __restrict__ minpack,
                              float* __restrict__ out) {
    int row = blockIdx.x;
    unsigned idx = (unsigned)(minpack[row] & 0xFFFFFFFFull);
    int lane = threadIdx.x;
    ((float4*)(out + (size_t)row * ND))[lane] =
        ((const float4*)(P + (size_t)idx * ND))[lane];
}

// ======================= fallback: exact fp32 path (small ws) ===============
#define BM1 128
#define BN1 128
#define BK1 32
#define LDA1 132

__global__ void psq_init_kernel(const float* __restrict__ P, float* __restrict__ psq,
                                unsigned long long* __restrict__ minpack) {
    int row  = blockIdx.x * 4 + (threadIdx.x >> 6);
    int lane = threadIdx.x & 63;
    float4 p4 = ((const float4*)(P + (size_t)row * ND))[lane];
    float s = p4.x*p4.x + p4.y*p4.y + p4.z*p4.z + p4.w*p4.w;
    #pragma unroll
    for (int off = 32; off > 0; off >>= 1) s += __shfl_down(s, off);
    if (lane == 0) psq[row] = s;
    int gid = blockIdx.x * blockDim.x + threadIdx.x;
    if (gid < NB) minpack[gid] = 0xFFFFFFFFFFFFFFFFull;
}

__global__ __launch_bounds__(256, 2)
void nn_main_kernel(const float* __restrict__ X, const float* __restrict__ P,
                    const float* __restrict__ psq,
                    unsigned long long* __restrict__ minpack) {
    __shared__ __align__(16) char smem_raw[2 * BK1 * LDA1 * 4];
    float (*As)[LDA1] = (float (*)[LDA1])smem_raw;
    float (*Bs)[LDA1] = (float (*)[LDA1])(smem_raw + BK1 * LDA1 * 4);
    const int bm  = blockIdx.y * BM1;
    const int bn  = blockIdx.x * BN1;
    const int tid = threadIdx.x;
    const int tx  = tid & 15;
    const int ty  = tid >> 4;
    float acc[8][8];
    #pragma unroll
    for (int i = 0; i < 8; ++i)
        #pragma unroll
        for (int j = 0; j < 8; ++j) acc[i][j] = 0.f;
    const int lrow = tid >> 3;
    const int lk   = (tid & 7) * 4;
    for (int k0 = 0; k0 < ND; k0 += BK1) {
        #pragma unroll
        for (int p = 0; p < 4; ++p) {
            int r = p * 32 + lrow;
            float4 aa = *(const float4*)(X + (size_t)(bm + r) * ND + k0 + lk);
            As[lk+0][r] = aa.x; As[lk+1][r] = aa.y; As[lk+2][r] = aa.z; As[lk+3][r] = aa.w;
            float4 bb = *(const float4*)(P + (size_t)(bn + r) * ND + k0 + lk);
            Bs[lk+0][r] = bb.x; Bs[lk+1][r] = bb.y; Bs[lk+2][r] = bb.z; Bs[lk+3][r] = bb.w;
        }
        __syncthreads();
        #pragma unroll 4
        for (int k = 0; k < BK1; ++k) {
            float4 a0 = *(const float4*)&As[k][ty*8];
            float4 a1 = *(const float4*)&As[k][ty*8 + 4];
            float4 b0 = *(const float4*)&Bs[k][tx*4];
            float4 b1 = *(const float4*)&Bs[k][64 + tx*4];
            float av2[8] = {a0.x,a0.y,a0.z,a0.w,a1.x,a1.y,a1.z,a1.w};
            float bv2[8] = {b0.x,b0.y,b0.z,b0.w,b1.x,b1.y,b1.z,b1.w};
            #pragma unroll
            for (int i = 0; i < 8; ++i)
                #pragma unroll
                for (int j = 0; j < 8; ++j)
                    acc[i][j] = fmaf(av2[i], bv2[j], acc[i][j]);
        }
        __syncthreads();
    }
    unsigned long long (*red)[16] = (unsigned long long (*)[16])smem_raw;
    float cj[8];
    int   jglob[8];
    #pragma unroll
    for (int j = 0; j < 8; ++j) {
        int c = (j < 4) ? (tx*4 + j) : (64 + tx*4 + (j - 4));
        jglob[j] = bn + c;
        cj[j]    = psq[bn + c];
    }
    #pragma unroll
    for (int i = 0; i < 8; ++i) {
        float bestv = 0.f; unsigned bidx = 0u; bool first = true;
        #pragma unroll
        for (int j = 0; j < 8; ++j) {
            float s = fmaf(-2.f, acc[i][j], cj[j]);
            if (first || s < bestv) { bestv = s; bidx = (unsigned)jglob[j]; first = false; }
        }
        unsigned u = fkey(bestv);
        red[ty*8 + i][tx] = ((unsigned long long)u << 32) | (unsigned long long)bidx;
    }
    __syncthreads();
    if (tid < BM1) {
        unsigned long long m = red[tid][0];
        #pragma unroll
        for (int t = 1; t < 16; ++t) m = umin64(m, red[tid][t]);
        atomicMin(&minpack[bm + tid], m);
    }
}

// ------------------------------------------------------------------- launch
extern "C" void kernel_launch(void* const* d_in, const int* in_sizes, int n_in,
                              void* d_out, int out_size, void* d_ws, size_t ws_size,
                              hipStream_t stream) {
    const float* X = (const float*)d_in[0];
    const float* P = (const float*)d_in[1];
    float* out = (float*)d_out;
    char* w = (char*)d_ws;

    if (ws_size >= WS_NEED) {
        float* psq = (float*)(w + OFF_PSQ);
        __bf16* Xb = (__bf16*)(w + OFF_XB);
        __bf16* Pb = (__bf16*)(w + OFF_PB);
        unsigned* blockmin = (unsigned*)(w + OFF_BM);
        unsigned long long* minpack = (unsigned long long*)(w + OFF_MP);
        unsigned* ctr   = (unsigned*)(w + OFF_CTR);
        unsigned* pairs = (unsigned*)(w + OFF_PAIRS);

        prep_kernel<<<(NP + NB) / 4, 256, 0, stream>>>(X, P, psq, Xb, Pb);
        nn_dpp_kernel<<<(NB / 128) * NSPLIT, 512, 0, stream>>>(Xb, Pb, psq,
                                                               blockmin);
        hipMemsetAsync(ctr, 0, 4, stream);     // Xb dead after screen
        cand_kernel<<<NB / 8, 512, 0, stream>>>(blockmin, pairs, ctr, minpack);
        rescore_bal_kernel<<<1024, 256, 0, stream>>>(X, P, psq, pairs, ctr,
                                                     minpack);
        gather_kernel<<<NB, 64, 0, stream>>>(P, minpack, out);
    } else {
        float* psq = (float*)w;
        unsigned long long* minpack = (unsigned long long*)(w + (size_t)NP * 4);
        psq_init_kernel<<<NP / 4, 256, 0, stream>>>(P, psq, minpack);
        dim3 grid(NP / BN1, NB / BM1);
        nn_main_kernel<<<grid, dim3(256), 0, stream>>>(X, P, psq, minpack);
        gather_kernel<<<NB, 64, 0, stream>>>(P, minpack, out);
    }
}

// Round 19
// 191.278 us; speedup vs baseline: 1.2330x; 1.0714x over previous
//
#include <hip/hip_runtime.h>
#include <stdint.h>

// L2 1-NN, B=4096 x[B,256] vs N=32768 P[N,256] fp32.
// Round 19: R16 pipeline (screen 98.8us proven) + fused wave-per-row rescore
// with R18's field-proven quad-per-column coalesced reads:
//  - per candidate group, 4 passes; lanes (l&3) cover one column's
//    consecutive 64B (4x fewer cache transactions, 4 independent FMA chains)
//  - row's X quarters preloaded ONCE per row into xr[16] regs
//  - quad-split summation (passed absmax 0 in R18)
// No pair list, no global atomics, no extra kernels (R18's +35us mistake).
// argmin_j (psq[j] - 2 x.p_j); x_sq drops out. Candidate-group set
// {groupmin <= approx_min + 2.0} provably contains the exact argmin.

#define NB 4096
#define NP 32768
#define ND 256
#define NG 512             // N / 64 column groups
#define MARGIN 2.0f
#define NSPLIT 8
#define CPB 4096           // cols per split (NP / NSPLIT)

typedef __attribute__((ext_vector_type(8))) __bf16 bf16x8;
typedef __attribute__((ext_vector_type(4))) __bf16 bf16x4;
typedef __attribute__((ext_vector_type(4))) float f32x4;

// ---- workspace layout (bytes) ----
static constexpr size_t OFF_PSQ = 0;                               // 32768 f32
static constexpr size_t OFF_XB  = 131072;                          // 4096x256 bf16
static constexpr size_t OFF_PB  = OFF_XB + (size_t)NB * ND * 2;    // 32768x256 bf16
static constexpr size_t OFF_BM  = OFF_PB + (size_t)NP * ND * 2;    // 4096x512 u32
static constexpr size_t WS_NEED = OFF_BM + (size_t)NB * NG * 4;    // 27,394,048

#define VMCNT(n) asm volatile("s_waitcnt vmcnt(" #n ")" ::: "memory")
#define LGKM(n)  asm volatile("s_waitcnt lgkmcnt(" #n ")" ::: "memory")

__device__ __forceinline__ void gload_lds16(const void* g, void* l) {
    __builtin_amdgcn_global_load_lds(
        (const __attribute__((address_space(1))) uint32_t*)g,
        (__attribute__((address_space(3))) uint32_t*)l, 16, 0, 0);
}
// 16-lane min-reduce on the VALU pipe (DPP); reduce lanes = one DPP row.
__device__ __forceinline__ float dppmin16(float v) {
    int x;
    x = __builtin_amdgcn_update_dpp(0, __float_as_int(v), 0xB1, 0xF, 0xF, true);
    v = fminf(v, __int_as_float(x));   // quad_perm xor1
    x = __builtin_amdgcn_update_dpp(0, __float_as_int(v), 0x4E, 0xF, 0xF, true);
    v = fminf(v, __int_as_float(x));   // quad_perm xor2
    x = __builtin_amdgcn_update_dpp(0, __float_as_int(v), 0x141, 0xF, 0xF, true);
    v = fminf(v, __int_as_float(x));   // row_half_mirror -> min over 8
    x = __builtin_amdgcn_update_dpp(0, __float_as_int(v), 0x140, 0xF, 0xF, true);
    v = fminf(v, __int_as_float(x));   // row_mirror      -> min over 16
    return v;
}
__device__ __forceinline__ unsigned fkey(float f) {
    unsigned u = __float_as_uint(f);
    return (u & 0x80000000u) ? ~u : (u | 0x80000000u);
}
__device__ __forceinline__ float fkey_inv(unsigned u) {
    unsigned o = (u & 0x80000000u) ? (u & 0x7FFFFFFFu) : ~u;
    return __uint_as_float(o);
}
__device__ __forceinline__ unsigned long long umin64(unsigned long long a,
                                                     unsigned long long b) {
    return a < b ? a : b;
}
__device__ __forceinline__ unsigned umin32(unsigned a, unsigned b) {
    return a < b ? a : b;
}

// ------------------------------------------------- prep: bf16 convert + psq
__global__ void prep_kernel(const float* __restrict__ X, const float* __restrict__ P,
                            float* __restrict__ psq, __bf16* __restrict__ Xb,
                            __bf16* __restrict__ Pb) {
    int row  = blockIdx.x * 4 + (threadIdx.x >> 6);  // one wave per row
    int lane = threadIdx.x & 63;
    if (row < NP) {
        f32x4 v = ((const f32x4*)(P + (size_t)row * ND))[lane];
        bf16x4 b;
        b.x = (__bf16)v.x; b.y = (__bf16)v.y; b.z = (__bf16)v.z; b.w = (__bf16)v.w;
        ((bf16x4*)(Pb + (size_t)row * ND))[lane] = b;
        float s = v.x*v.x + v.y*v.y + v.z*v.z + v.w*v.w;
        #pragma unroll
        for (int off = 32; off > 0; off >>= 1) s += __shfl_down(s, off);
        if (lane == 0) psq[row] = s;
    } else {
        int r = row - NP;   // < NB
        f32x4 v = ((const f32x4*)(X + (size_t)r * ND))[lane];
        bf16x4 b;
        b.x = (__bf16)v.x; b.y = (__bf16)v.y; b.z = (__bf16)v.z; b.w = (__bf16)v.w;
        ((bf16x4*)(Xb + (size_t)r * ND))[lane] = b;
    }
}

// ------------- A-in-LDS N-sweep screen (R16, byte-identical: 98.8us) --------
__global__ __launch_bounds__(512, 2)
void nn_dpp_kernel(const __bf16* __restrict__ Xb, const __bf16* __restrict__ Pb,
                   const float* __restrict__ psq,
                   unsigned* __restrict__ blockmin) {
    __shared__ __align__(16) char smem[163840];
    char* ring  = smem;                                   // 4 x 16KB
    char* A_lds = smem + 65536;                           // 64KB
    unsigned (*tbl)[64] = (unsigned (*)[64])(smem + 131072);  // 128x64 u32

    const int tid  = threadIdx.x;
    const int lane = tid & 63;
    const int wave = tid >> 6;
    const int wm = wave >> 2, wn = wave & 3;
    const int bid    = blockIdx.x;
    const int nsplit = bid & 7;
    const int mblk   = bid >> 3;
    const int bm     = mblk * 128;
    const int Nb     = nsplit * CPB;
    const int fr = lane & 15, kg = lane >> 4;
    const int wbase16 = (tid & ~63) * 16;

    f32x4 acc[4][4];
    #pragma unroll
    for (int i = 0; i < 4; ++i)
        #pragma unroll
        for (int j = 0; j < 4; ++j) acc[i][j] = (f32x4){0.f, 0.f, 0.f, 0.f};

    auto stage = [&](int p) {
        char* dst = ring + (size_t)(p & 3) * 16384;
        const int colb = Nb + (p >> 3) * 256;
        const int kq   = p & 7;
        #pragma unroll
        for (int i = 0; i < 2; ++i) {
            const int c = i * 512 + tid;          // chunk 0..1023
            const int fn = c >> 6;
            const int l  = c & 63;
            gload_lds16(Pb + (size_t)(colb + fn * 16 + (l & 15)) * ND +
                            kq * 32 + (l >> 4) * 8,
                        dst + i * 8192 + wbase16);
        }
    };

    // ---- prologue: A (8 issues) + pieces 0..2 ----
    #pragma unroll
    for (int i = 0; i < 8; ++i) {
        const int c  = i * 512 + tid;              // chunk 0..4095
        const int q  = c >> 9;                     // k-slab 0..7
        const int fm = (c >> 6) & 7;               // 16-row frag 0..7
        const int l  = c & 63;
        gload_lds16(Xb + (size_t)(bm + fm * 16 + (l & 15)) * ND +
                        q * 32 + (l >> 4) * 8,
                    A_lds + (size_t)(i * 512) * 16 + wbase16);
    }
    stage(0); stage(1); stage(2);
    VMCNT(4);                                  // A(8)+s0 drained; s1,s2 fly
    __builtin_amdgcn_s_barrier();              // A + slot0 published
    __builtin_amdgcn_sched_barrier(0);

    bf16x8 av[2][4], bv[2][4];
    #pragma unroll
    for (int mi = 0; mi < 4; ++mi)
        av[0][mi] = *(const bf16x8*)(A_lds +
            (size_t)((wm * 4 + mi) * 64 + lane) * 16);
    #pragma unroll
    for (int ni = 0; ni < 4; ++ni)
        bv[0][ni] = *(const bf16x8*)(ring +
            (size_t)((wn * 4 + ni) * 64 + lane) * 16);

    #pragma unroll 1
    for (int nt = 0; nt < 16; ++nt) {
        float cq[4];
        #pragma unroll
        for (int q = 0; q < 8; ++q) {
            const int t = nt * 8 + q;
            const int cur = q & 1, nxt = cur ^ 1;
            if (t >= 126)            { VMCNT(0); }
            else if (q == 1 || q == 2) { VMCNT(6); }
            else                     { VMCNT(2); }
            __builtin_amdgcn_s_barrier();      // ALL waves' stage(t+1) done
            __builtin_amdgcn_sched_barrier(0);
            if (t < 127) {
                const int qn = (q + 1) & 7;
                #pragma unroll
                for (int mi = 0; mi < 4; ++mi)
                    av[nxt][mi] = *(const bf16x8*)(A_lds +
                        (size_t)((qn * 8 + wm * 4 + mi) * 64 + lane) * 16);
                const char* pc = ring + (size_t)((t + 1) & 3) * 16384;
                #pragma unroll
                for (int ni = 0; ni < 4; ++ni)
                    bv[nxt][ni] = *(const bf16x8*)(pc +
                        (size_t)((wn * 4 + ni) * 64 + lane) * 16);
            }
            if (t <= 124) stage(t + 3);
            if (q == 0) {
                const int colb = Nb + nt * 256 + wn * 64;
                #pragma unroll
                for (int ni = 0; ni < 4; ++ni)
                    cq[ni] = psq[colb + ni * 16 + fr];   // drains by q==3
            }
            __builtin_amdgcn_s_setprio(1);
            #pragma unroll
            for (int mi = 0; mi < 4; ++mi)
                #pragma unroll
                for (int ni = 0; ni < 4; ++ni)
                    acc[mi][ni] = __builtin_amdgcn_mfma_f32_16x16x32_bf16(
                        av[cur][mi], bv[cur][ni], acc[mi][ni], 0, 0, 0);
            __builtin_amdgcn_s_setprio(0);

            if (q == 7) {
                // ---- epilogue: VALU-only reduce -> LDS key table ----
                const int g = nt * 4 + wn;
                #pragma unroll
                for (int mi = 0; mi < 4; ++mi) {
                    #pragma unroll
                    for (int r = 0; r < 4; ++r) {
                        float d = fmaf(-2.f, acc[mi][0][r], cq[0]);
                        #pragma unroll
                        for (int ni = 1; ni < 4; ++ni)
                            d = fminf(d, fmaf(-2.f, acc[mi][ni][r], cq[ni]));
                        d = dppmin16(d);
                        if (fr == 0)
                            tbl[wm * 64 + mi * 16 + kg * 4 + r][g] = fkey(d);
                    }
                }
                #pragma unroll
                for (int i = 0; i < 4; ++i)
                    #pragma unroll
                    for (int j = 0; j < 4; ++j)
                        acc[i][j] = (f32x4){0.f, 0.f, 0.f, 0.f};
            }
        }
    }

    // ---- flush key table: 8192 u32, coalesced ----
    __syncthreads();
    #pragma unroll
    for (int i = 0; i < 8; ++i) {
        const int f2  = i * 512 + tid;             // uint2 index
        uint2 v = ((const uint2*)tbl)[f2];
        const int idx = f2 * 2;
        const int row = idx >> 6, col = idx & 63;
        *(uint2*)&blockmin[(size_t)(bm + row) * NG + nsplit * 64 + col] = v;
    }
}

// ------ rescore: wave-per-row, quad-per-column coalesced (R18-proven) -------
// Per row: candidate groups via LDS list (R16-proven); xr[16] = row's X
// quarters loaded ONCE; per group, 4 passes: lanes (l&3) cover one column's
// consecutive 64B; quad-split sum (2 shfl_xor) -> key; wave u64 min -> gather.
__global__ __launch_bounds__(512, 2)
void rescore_q_kernel(const float* __restrict__ X, const float* __restrict__ P,
                      const float* __restrict__ psq,
                      const unsigned* __restrict__ blockmin,
                      float* __restrict__ out) {
    __shared__ float Xs[8][256];
    __shared__ unsigned short wcand[8][512];
    __shared__ int wcnt[8];

    const int tid = threadIdx.x, lane = tid & 63, wv = tid >> 6;
    const int row = blockIdx.x * 8 + wv;

    ((f32x4*)Xs[wv])[lane] = ((const f32x4*)(X + (size_t)row * ND))[lane];
    if (lane == 0) wcnt[wv] = 0;

    const unsigned* bmr = blockmin + (size_t)row * NG;
    uint4 ka = ((const uint4*)bmr)[lane * 2];
    uint4 kb = ((const uint4*)bmr)[lane * 2 + 1];
    unsigned km = umin32(umin32(umin32(ka.x, ka.y), umin32(ka.z, ka.w)),
                         umin32(umin32(kb.x, kb.y), umin32(kb.z, kb.w)));
    #pragma unroll
    for (int m = 1; m < 64; m <<= 1) km = umin32(km, __shfl_xor(km, m));
    const unsigned thr = fkey(fkey_inv(km) + MARGIN);

    const unsigned k8[8] = {ka.x, ka.y, ka.z, ka.w, kb.x, kb.y, kb.z, kb.w};
    #pragma unroll
    for (int i = 0; i < 8; ++i)
        if (k8[i] <= thr)
            wcand[wv][atomicAdd(&wcnt[wv], 1)] = (unsigned short)(lane * 8 + i);
    LGKM(0);                             // same-wave DS ops complete, in order
    const int n = wcnt[wv];

    // lane's quarter of the row: f32x4 indices (lane&3)+4i, reused all groups
    f32x4 xr[16];
    #pragma unroll
    for (int i = 0; i < 16; ++i)
        xr[i] = ((const f32x4*)Xs[wv])[(lane & 3) + i * 4];

    unsigned long long best = 0xFFFFFFFFFFFFFFFFull;
    for (int c = 0; c < n; ++c) {
        const int g = wcand[wv][c];
        #pragma unroll
        for (int cc = 0; cc < 4; ++cc) {
            const int col = g * 64 + cc * 16 + (lane >> 2);
            const f32x4* p4 = (const f32x4*)(P + (size_t)col * ND);
            float s = 0.f;
            #pragma unroll
            for (int i = 0; i < 16; ++i) {
                f32x4 pv = p4[(lane & 3) + i * 4], xv = xr[i];
                s = fmaf(xv.x, pv.x, s); s = fmaf(xv.y, pv.y, s);
                s = fmaf(xv.z, pv.z, s); s = fmaf(xv.w, pv.w, s);
            }
            s += __shfl_xor(s, 1);
            s += __shfl_xor(s, 2);           // full quad sum on all 4 lanes
            unsigned long long key = 0xFFFFFFFFFFFFFFFFull;
            if ((lane & 3) == 0) {
                float d = fmaf(-2.f, s, psq[col]);
                key = ((unsigned long long)fkey(d) << 32) |
                      (unsigned long long)(unsigned)col;
            }
            best = umin64(best, key);
        }
    }
    #pragma unroll
    for (int m = 1; m < 64; m <<= 1)
        best = umin64(best, __shfl_xor(best, m));
    const unsigned bc = (unsigned)(best & 0xFFFFFFFFull);
    ((f32x4*)(out + (size_t)row * ND))[lane] =
        ((const f32x4*)(P + (size_t)bc * ND))[lane];
}

// ======================= fallback: exact fp32 path (small ws) ===============
#define BM1 128
#define BN1 128
#define BK1 32
#define LDA1 132

__global__ void psq_init_kernel(const float* __restrict__ P, float* __restrict__ psq,
                                unsigned long long* __restrict__ minpack) {
    int row  = blockIdx.x * 4 + (threadIdx.x >> 6);
    int lane = threadIdx.x & 63;
    float4 p4 = ((const float4*)(P + (size_t)row * ND))[lane];
    float s = p4.x*p4.x + p4.y*p4.y + p4.z*p4.z + p4.w*p4.w;
    #pragma unroll
    for (int off = 32; off > 0; off >>= 1) s += __shfl_down(s, off);
    if (lane == 0) psq[row] = s;
    int gid = blockIdx.x * blockDim.x + threadIdx.x;
    if (gid < NB) minpack[gid] = 0xFFFFFFFFFFFFFFFFull;
}

__global__ __launch_bounds__(256, 2)
void nn_main_kernel(const float* __restrict__ X, const float* __restrict__ P,
                    const float* __restrict__ psq,
                    unsigned long long* __restrict__ minpack) {
    __shared__ __align__(16) char smem_raw[2 * BK1 * LDA1 * 4];
    float (*As)[LDA1] = (float (*)[LDA1])smem_raw;
    float (*Bs)[LDA1] = (float (*)[LDA1])(smem_raw + BK1 * LDA1 * 4);
    const int bm  = blockIdx.y * BM1;
    const int bn  = blockIdx.x * BN1;
    const int tid = threadIdx.x;
    const int tx  = tid & 15;
    const int ty  = tid >> 4;
    float acc[8][8];
    #pragma unroll
    for (int i = 0; i < 8; ++i)
        #pragma unroll
        for (int j = 0; j < 8; ++j) acc[i][j] = 0.f;
    const int lrow = tid >> 3;
    const int lk   = (tid & 7) * 4;
    for (int k0 = 0; k0 < ND; k0 += BK1) {
        #pragma unroll
        for (int p = 0; p < 4; ++p) {
            int r = p * 32 + lrow;
            float4 aa = *(const float4*)(X + (size_t)(bm + r) * ND + k0 + lk);
            As[lk+0][r] = aa.x; As[lk+1][r] = aa.y; As[lk+2][r] = aa.z; As[lk+3][r] = aa.w;
            float4 bb = *(const float4*)(P + (size_t)(bn + r) * ND + k0 + lk);
            Bs[lk+0][r] = bb.x; Bs[lk+1][r] = bb.y; Bs[lk+2][r] = bb.z; Bs[lk+3][r] = bb.w;
        }
        __syncthreads();
        #pragma unroll 4
        for (int k = 0; k < BK1; ++k) {
            float4 a0 = *(const float4*)&As[k][ty*8];
            float4 a1 = *(const float4*)&As[k][ty*8 + 4];
            float4 b0 = *(const float4*)&Bs[k][tx*4];
            float4 b1 = *(const float4*)&Bs[k][64 + tx*4];
            float av2[8] = {a0.x,a0.y,a0.z,a0.w,a1.x,a1.y,a1.z,a1.w};
            float bv2[8] = {b0.x,b0.y,b0.z,b0.w,b1.x,b1.y,b1.z,b1.w};
            #pragma unroll
            for (int i = 0; i < 8; ++i)
                #pragma unroll
                for (int j = 0; j < 8; ++j)
                    acc[i][j] = fmaf(av2[i], bv2[j], acc[i][j]);
        }
        __syncthreads();
    }
    unsigned long long (*red)[16] = (unsigned long long (*)[16])smem_raw;
    float cj[8];
    int   jglob[8];
    #pragma unroll
    for (int j = 0; j < 8; ++j) {
        int c = (j < 4) ? (tx*4 + j) : (64 + tx*4 + (j - 4));
        jglob[j] = bn + c;
        cj[j]    = psq[bn + c];
    }
    #pragma unroll
    for (int i = 0; i < 8; ++i) {
        float bestv = 0.f; unsigned bidx = 0u; bool first = true;
        #pragma unroll
        for (int j = 0; j < 8; ++j) {
            float s = fmaf(-2.f, acc[i][j], cj[j]);
            if (first || s < bestv) { bestv = s; bidx = (unsigned)jglob[j]; first = false; }
        }
        unsigned u = fkey(bestv);
        red[ty*8 + i][tx] = ((unsigned long long)u << 32) | (unsigned long long)bidx;
    }
    __syncthreads();
    if (tid < BM1) {
        unsigned long long m = red[tid][0];
        #pragma unroll
        for (int t = 1; t < 16; ++t) m = umin64(m, red[tid][t]);
        atomicMin(&minpack[bm + tid], m);
    }
}

__global__ void gather_kernel(const float* __restrict__ P,
                              const unsigned long long* __restrict__ minpack,
                              float* __restrict__ out) {
    int row = blockIdx.x;
    unsigned idx = (unsigned)(minpack[row] & 0xFFFFFFFFull);
    int lane = threadIdx.x;
    ((float4*)(out + (size_t)row * ND))[lane] =
        ((const float4*)(P + (size_t)idx * ND))[lane];
}

// ------------------------------------------------------------------- launch
extern "C" void kernel_launch(void* const* d_in, const int* in_sizes, int n_in,
                              void* d_out, int out_size, void* d_ws, size_t ws_size,
                              hipStream_t stream) {
    const float* X = (const float*)d_in[0];
    const float* P = (const float*)d_in[1];
    float* out = (float*)d_out;
    char* w = (char*)d_ws;

    if (ws_size >= WS_NEED) {
        float* psq = (float*)(w + OFF_PSQ);
        __bf16* Xb = (__bf16*)(w + OFF_XB);
        __bf16* Pb = (__bf16*)(w + OFF_PB);
        unsigned* blockmin = (unsigned*)(w + OFF_BM);

        prep_kernel<<<(NP + NB) / 4, 256, 0, stream>>>(X, P, psq, Xb, Pb);
        nn_dpp_kernel<<<(NB / 128) * NSPLIT, 512, 0, stream>>>(Xb, Pb, psq,
                                                               blockmin);
        rescore_q_kernel<<<NB / 8, 512, 0, stream>>>(X, P, psq, blockmin, out);
    } else {
        float* psq = (float*)w;
        unsigned long long* minpack = (unsigned long long*)(w + (size_t)NP * 4);
        psq_init_kernel<<<NP / 4, 256, 0, stream>>>(P, psq, minpack);
        dim3 grid(NP / BN1, NB / BM1);
        nn_main_kernel<<<grid, dim3(256), 0, stream>>>(X, P, psq, minpack);
        gather_kernel<<<NB, 64, 0, stream>>>(P, minpack, out);
    }
}

// Round 20
// 170.449 us; speedup vs baseline: 1.3837x; 1.1222x over previous
//
#include <hip/hip_runtime.h>
#include <stdint.h>

// L2 1-NN, B=4096 x[B,256] vs N=32768 P[N,256] fp32.
// Round 20 (final): revert to the Round-16 configuration — the measured
// global best (169.9us total, absmax 0):
//   prep (bf16 convert + psq, ~35us BW-bound)
//   -> A-in-LDS N-sweep bf16 MFMA screen with DPP epilogue + LDS key table
//      (98.8us, 695 TF effective, VGPR 96, zero spill)
//   -> fused wave-per-row fp32 margin rescore + gather (~30us).
// R17 (two-stage filter), R18 (pair-list balancing), R19 (quad-coalescing)
// each regressed the rescore; R16's simple form is the empirical minimum.
// argmin_j (psq[j] - 2 x.p_j); x_sq drops out. Candidate-group set
// {groupmin <= approx_min + 2.0} provably contains the exact argmin
// (MARGIN >= 2*max bf16 screening error).

#define NB 4096
#define NP 32768
#define ND 256
#define NG 512             // N / 64 column groups
#define MARGIN 2.0f
#define NSPLIT 8
#define CPB 4096           // cols per split (NP / NSPLIT)

typedef __attribute__((ext_vector_type(8))) __bf16 bf16x8;
typedef __attribute__((ext_vector_type(4))) __bf16 bf16x4;
typedef __attribute__((ext_vector_type(4))) float f32x4;

// ---- workspace layout (bytes) ----
static constexpr size_t OFF_PSQ = 0;                               // 32768 f32
static constexpr size_t OFF_XB  = 131072;                          // 4096x256 bf16
static constexpr size_t OFF_PB  = OFF_XB + (size_t)NB * ND * 2;    // 32768x256 bf16
static constexpr size_t OFF_BM  = OFF_PB + (size_t)NP * ND * 2;    // 4096x512 u32
static constexpr size_t WS_NEED = OFF_BM + (size_t)NB * NG * 4;    // 27,394,048

#define VMCNT(n) asm volatile("s_waitcnt vmcnt(" #n ")" ::: "memory")
#define LGKM(n)  asm volatile("s_waitcnt lgkmcnt(" #n ")" ::: "memory")

__device__ __forceinline__ void gload_lds16(const void* g, void* l) {
    __builtin_amdgcn_global_load_lds(
        (const __attribute__((address_space(1))) uint32_t*)g,
        (__attribute__((address_space(3))) uint32_t*)l, 16, 0, 0);
}
// 16-lane min-reduce on the VALU pipe (DPP); reduce lanes = one DPP row.
__device__ __forceinline__ float dppmin16(float v) {
    int x;
    x = __builtin_amdgcn_update_dpp(0, __float_as_int(v), 0xB1, 0xF, 0xF, true);
    v = fminf(v, __int_as_float(x));   // quad_perm xor1
    x = __builtin_amdgcn_update_dpp(0, __float_as_int(v), 0x4E, 0xF, 0xF, true);
    v = fminf(v, __int_as_float(x));   // quad_perm xor2
    x = __builtin_amdgcn_update_dpp(0, __float_as_int(v), 0x141, 0xF, 0xF, true);
    v = fminf(v, __int_as_float(x));   // row_half_mirror -> min over 8
    x = __builtin_amdgcn_update_dpp(0, __float_as_int(v), 0x140, 0xF, 0xF, true);
    v = fminf(v, __int_as_float(x));   // row_mirror      -> min over 16
    return v;
}
__device__ __forceinline__ unsigned fkey(float f) {
    unsigned u = __float_as_uint(f);
    return (u & 0x80000000u) ? ~u : (u | 0x80000000u);
}
__device__ __forceinline__ float fkey_inv(unsigned u) {
    unsigned o = (u & 0x80000000u) ? (u & 0x7FFFFFFFu) : ~u;
    return __uint_as_float(o);
}
__device__ __forceinline__ unsigned long long umin64(unsigned long long a,
                                                     unsigned long long b) {
    return a < b ? a : b;
}
__device__ __forceinline__ unsigned umin32(unsigned a, unsigned b) {
    return a < b ? a : b;
}

// ------------------------------------------------- prep: bf16 convert + psq
__global__ void prep_kernel(const float* __restrict__ X, const float* __restrict__ P,
                            float* __restrict__ psq, __bf16* __restrict__ Xb,
                            __bf16* __restrict__ Pb) {
    int row  = blockIdx.x * 4 + (threadIdx.x >> 6);  // one wave per row
    int lane = threadIdx.x & 63;
    if (row < NP) {
        f32x4 v = ((const f32x4*)(P + (size_t)row * ND))[lane];
        bf16x4 b;
        b.x = (__bf16)v.x; b.y = (__bf16)v.y; b.z = (__bf16)v.z; b.w = (__bf16)v.w;
        ((bf16x4*)(Pb + (size_t)row * ND))[lane] = b;
        float s = v.x*v.x + v.y*v.y + v.z*v.z + v.w*v.w;
        #pragma unroll
        for (int off = 32; off > 0; off >>= 1) s += __shfl_down(s, off);
        if (lane == 0) psq[row] = s;
    } else {
        int r = row - NP;   // < NB
        f32x4 v = ((const f32x4*)(X + (size_t)r * ND))[lane];
        bf16x4 b;
        b.x = (__bf16)v.x; b.y = (__bf16)v.y; b.z = (__bf16)v.z; b.w = (__bf16)v.w;
        ((bf16x4*)(Xb + (size_t)r * ND))[lane] = b;
    }
}

// ------------- A-in-LDS N-sweep screen, DPP epilogue, LDS key table ---------
// Grid 256 = 32 mblk x 8 split (bid&7 -> XCD-local 2MB B-panel); 1 block/CU.
// 512 thr = 8 waves (wm 0..1 x wn 0..3); wave tile 64 rows x 64 cols,
// acc[4][4]. Sweep: 128 bodies (body t: n-tile t>>3, 32-k slab t&7). B piece
// = 256 cols x 32 k = 16KB; ring 4x16KB, slot t&3, stage lead 3.
// Body t: VMCNT(table) [own stage(t+1) drained]; s_barrier [ALL waves'
// stage(t+1) published]; sched_barrier; read av/bv for t+1 (read-ahead,
// proven WAR chain); stage(t+3); q==0: prefetch cq[4]; 16 MFMA on [cur];
// q==7: DPP-reduce epilogue -> LDS tbl (no VMEM). Flush tbl once at end.
__global__ __launch_bounds__(512, 2)
void nn_dpp_kernel(const __bf16* __restrict__ Xb, const __bf16* __restrict__ Pb,
                   const float* __restrict__ psq,
                   unsigned* __restrict__ blockmin) {
    __shared__ __align__(16) char smem[163840];
    char* ring  = smem;                                   // 4 x 16KB
    char* A_lds = smem + 65536;                           // 64KB
    unsigned (*tbl)[64] = (unsigned (*)[64])(smem + 131072);  // 128x64 u32

    const int tid  = threadIdx.x;
    const int lane = tid & 63;
    const int wave = tid >> 6;
    const int wm = wave >> 2, wn = wave & 3;
    const int bid    = blockIdx.x;
    const int nsplit = bid & 7;
    const int mblk   = bid >> 3;
    const int bm     = mblk * 128;
    const int Nb     = nsplit * CPB;
    const int fr = lane & 15, kg = lane >> 4;
    const int wbase16 = (tid & ~63) * 16;

    f32x4 acc[4][4];
    #pragma unroll
    for (int i = 0; i < 4; ++i)
        #pragma unroll
        for (int j = 0; j < 4; ++j) acc[i][j] = (f32x4){0.f, 0.f, 0.f, 0.f};

    auto stage = [&](int p) {
        char* dst = ring + (size_t)(p & 3) * 16384;
        const int colb = Nb + (p >> 3) * 256;
        const int kq   = p & 7;
        #pragma unroll
        for (int i = 0; i < 2; ++i) {
            const int c = i * 512 + tid;          // chunk 0..1023
            const int fn = c >> 6;
            const int l  = c & 63;
            gload_lds16(Pb + (size_t)(colb + fn * 16 + (l & 15)) * ND +
                            kq * 32 + (l >> 4) * 8,
                        dst + i * 8192 + wbase16);
        }
    };

    // ---- prologue: A (8 issues) + pieces 0..2 ----
    #pragma unroll
    for (int i = 0; i < 8; ++i) {
        const int c  = i * 512 + tid;              // chunk 0..4095
        const int q  = c >> 9;                     // k-slab 0..7
        const int fm = (c >> 6) & 7;               // 16-row frag 0..7
        const int l  = c & 63;
        gload_lds16(Xb + (size_t)(bm + fm * 16 + (l & 15)) * ND +
                        q * 32 + (l >> 4) * 8,
                    A_lds + (size_t)(i * 512) * 16 + wbase16);
    }
    stage(0); stage(1); stage(2);
    VMCNT(4);                                  // A(8)+s0 drained; s1,s2 fly
    __builtin_amdgcn_s_barrier();              // A + slot0 published
    __builtin_amdgcn_sched_barrier(0);

    bf16x8 av[2][4], bv[2][4];
    #pragma unroll
    for (int mi = 0; mi < 4; ++mi)
        av[0][mi] = *(const bf16x8*)(A_lds +
            (size_t)((wm * 4 + mi) * 64 + lane) * 16);
    #pragma unroll
    for (int ni = 0; ni < 4; ++ni)
        bv[0][ni] = *(const bf16x8*)(ring +
            (size_t)((wn * 4 + ni) * 64 + lane) * 16);

    #pragma unroll 1
    for (int nt = 0; nt < 16; ++nt) {
        float cq[4];
        #pragma unroll
        for (int q = 0; q < 8; ++q) {
            const int t = nt * 8 + q;
            const int cur = q & 1, nxt = cur ^ 1;
            if (t >= 126)            { VMCNT(0); }
            else if (q == 1 || q == 2) { VMCNT(6); }
            else                     { VMCNT(2); }
            __builtin_amdgcn_s_barrier();      // ALL waves' stage(t+1) done
            __builtin_amdgcn_sched_barrier(0);
            if (t < 127) {
                const int qn = (q + 1) & 7;
                #pragma unroll
                for (int mi = 0; mi < 4; ++mi)
                    av[nxt][mi] = *(const bf16x8*)(A_lds +
                        (size_t)((qn * 8 + wm * 4 + mi) * 64 + lane) * 16);
                const char* pc = ring + (size_t)((t + 1) & 3) * 16384;
                #pragma unroll
                for (int ni = 0; ni < 4; ++ni)
                    bv[nxt][ni] = *(const bf16x8*)(pc +
                        (size_t)((wn * 4 + ni) * 64 + lane) * 16);
            }
            if (t <= 124) stage(t + 3);
            if (q == 0) {
                const int colb = Nb + nt * 256 + wn * 64;
                #pragma unroll
                for (int ni = 0; ni < 4; ++ni)
                    cq[ni] = psq[colb + ni * 16 + fr];   // drains by q==3
            }
            __builtin_amdgcn_s_setprio(1);
            #pragma unroll
            for (int mi = 0; mi < 4; ++mi)
                #pragma unroll
                for (int ni = 0; ni < 4; ++ni)
                    acc[mi][ni] = __builtin_amdgcn_mfma_f32_16x16x32_bf16(
                        av[cur][mi], bv[cur][ni], acc[mi][ni], 0, 0, 0);
            __builtin_amdgcn_s_setprio(0);

            if (q == 7) {
                // ---- epilogue: VALU-only reduce -> LDS key table ----
                const int g = nt * 4 + wn;
                #pragma unroll
                for (int mi = 0; mi < 4; ++mi) {
                    #pragma unroll
                    for (int r = 0; r < 4; ++r) {
                        float d = fmaf(-2.f, acc[mi][0][r], cq[0]);
                        #pragma unroll
                        for (int ni = 1; ni < 4; ++ni)
                            d = fminf(d, fmaf(-2.f, acc[mi][ni][r], cq[ni]));
                        d = dppmin16(d);
                        if (fr == 0)
                            tbl[wm * 64 + mi * 16 + kg * 4 + r][g] = fkey(d);
                    }
                }
                #pragma unroll
                for (int i = 0; i < 4; ++i)
                    #pragma unroll
                    for (int j = 0; j < 4; ++j)
                        acc[i][j] = (f32x4){0.f, 0.f, 0.f, 0.f};
            }
        }
    }

    // ---- flush key table: 8192 u32, coalesced ----
    __syncthreads();
    #pragma unroll
    for (int i = 0; i < 8; ++i) {
        const int f2  = i * 512 + tid;             // uint2 index
        uint2 v = ((const uint2*)tbl)[f2];
        const int idx = f2 * 2;
        const int row = idx >> 6, col = idx & 63;
        *(uint2*)&blockmin[(size_t)(bm + row) * NG + nsplit * 64 + col] = v;
    }
}

// ---------------- rescore: one wave per row, barrier-free -------------------
__global__ __launch_bounds__(512, 2)
void rescore_wave_kernel(const float* __restrict__ X, const float* __restrict__ P,
                         const float* __restrict__ psq,
                         const unsigned* __restrict__ blockmin,
                         float* __restrict__ out) {
    __shared__ float Xs[8][256];
    __shared__ unsigned short wcand[8][512];
    __shared__ int wcnt[8];

    const int tid = threadIdx.x, lane = tid & 63, wv = tid >> 6;
    const int row = blockIdx.x * 8 + wv;

    ((f32x4*)Xs[wv])[lane] = ((const f32x4*)(X + (size_t)row * ND))[lane];
    if (lane == 0) wcnt[wv] = 0;

    const unsigned* bmr = blockmin + (size_t)row * NG;
    uint4 ka = ((const uint4*)bmr)[lane * 2];
    uint4 kb = ((const uint4*)bmr)[lane * 2 + 1];
    unsigned km = umin32(umin32(umin32(ka.x, ka.y), umin32(ka.z, ka.w)),
                         umin32(umin32(kb.x, kb.y), umin32(kb.z, kb.w)));
    #pragma unroll
    for (int m = 1; m < 64; m <<= 1) km = umin32(km, __shfl_xor(km, m));
    const unsigned thr = fkey(fkey_inv(km) + MARGIN);

    const unsigned k8[8] = {ka.x, ka.y, ka.z, ka.w, kb.x, kb.y, kb.z, kb.w};
    #pragma unroll
    for (int i = 0; i < 8; ++i)
        if (k8[i] <= thr)
            wcand[wv][atomicAdd(&wcnt[wv], 1)] = (unsigned short)(lane * 8 + i);
    LGKM(0);                             // same-wave DS ops complete, in order
    const int n = wcnt[wv];

    unsigned long long best = 0xFFFFFFFFFFFFFFFFull;
    const f32x4* x4 = (const f32x4*)Xs[wv];
    for (int c = 0; c < n; ++c) {
        const int col = (int)wcand[wv][c] * 64 + lane;
        const f32x4* p4 = (const f32x4*)(P + (size_t)col * ND);
        float s = 0.f;
        #pragma unroll 16
        for (int i = 0; i < 64; ++i) {
            f32x4 pv = p4[i], xv = x4[i];
            s = fmaf(xv.x, pv.x, s); s = fmaf(xv.y, pv.y, s);
            s = fmaf(xv.z, pv.z, s); s = fmaf(xv.w, pv.w, s);
        }
        float d = fmaf(-2.f, s, psq[col]);
        best = umin64(best, ((unsigned long long)fkey(d) << 32) |
                            (unsigned long long)(unsigned)col);
    }
    #pragma unroll
    for (int m = 1; m < 64; m <<= 1)
        best = umin64(best, __shfl_xor(best, m));
    const unsigned bc = (unsigned)(best & 0xFFFFFFFFull);
    ((f32x4*)(out + (size_t)row * ND))[lane] =
        ((const f32x4*)(P + (size_t)bc * ND))[lane];
}

// ======================= fallback: exact fp32 path (small ws) ===============
#define BM1 128
#define BN1 128
#define BK1 32
#define LDA1 132

__global__ void psq_init_kernel(const float* __restrict__ P, float* __restrict__ psq,
                                unsigned long long* __restrict__ minpack) {
    int row  = blockIdx.x * 4 + (threadIdx.x >> 6);
    int lane = threadIdx.x & 63;
    float4 p4 = ((const float4*)(P + (size_t)row * ND))[lane];
    float s = p4.x*p4.x + p4.y*p4.y + p4.z*p4.z + p4.w*p4.w;
    #pragma unroll
    for (int off = 32; off > 0; off >>= 1) s += __shfl_down(s, off);
    if (lane == 0) psq[row] = s;
    int gid = blockIdx.x * blockDim.x + threadIdx.x;
    if (gid < NB) minpack[gid] = 0xFFFFFFFFFFFFFFFFull;
}

__global__ __launch_bounds__(256, 2)
void nn_main_kernel(const float* __restrict__ X, const float* __restrict__ P,
                    const float* __restrict__ psq,
                    unsigned long long* __restrict__ minpack) {
    __shared__ __align__(16) char smem_raw[2 * BK1 * LDA1 * 4];
    float (*As)[LDA1] = (float (*)[LDA1])smem_raw;
    float (*Bs)[LDA1] = (float (*)[LDA1])(smem_raw + BK1 * LDA1 * 4);
    const int bm  = blockIdx.y * BM1;
    const int bn  = blockIdx.x * BN1;
    const int tid = threadIdx.x;
    const int tx  = tid & 15;
    const int ty  = tid >> 4;
    float acc[8][8];
    #pragma unroll
    for (int i = 0; i < 8; ++i)
        #pragma unroll
        for (int j = 0; j < 8; ++j) acc[i][j] = 0.f;
    const int lrow = tid >> 3;
    const int lk   = (tid & 7) * 4;
    for (int k0 = 0; k0 < ND; k0 += BK1) {
        #pragma unroll
        for (int p = 0; p < 4; ++p) {
            int r = p * 32 + lrow;
            float4 aa = *(const float4*)(X + (size_t)(bm + r) * ND + k0 + lk);
            As[lk+0][r] = aa.x; As[lk+1][r] = aa.y; As[lk+2][r] = aa.z; As[lk+3][r] = aa.w;
            float4 bb = *(const float4*)(P + (size_t)(bn + r) * ND + k0 + lk);
            Bs[lk+0][r] = bb.x; Bs[lk+1][r] = bb.y; Bs[lk+2][r] = bb.z; Bs[lk+3][r] = bb.w;
        }
        __syncthreads();
        #pragma unroll 4
        for (int k = 0; k < BK1; ++k) {
            float4 a0 = *(const float4*)&As[k][ty*8];
            float4 a1 = *(const float4*)&As[k][ty*8 + 4];
            float4 b0 = *(const float4*)&Bs[k][tx*4];
            float4 b1 = *(const float4*)&Bs[k][64 + tx*4];
            float av2[8] = {a0.x,a0.y,a0.z,a0.w,a1.x,a1.y,a1.z,a1.w};
            float bv2[8] = {b0.x,b0.y,b0.z,b0.w,b1.x,b1.y,b1.z,b1.w};
            #pragma unroll
            for (int i = 0; i < 8; ++i)
                #pragma unroll
                for (int j = 0; j < 8; ++j)
                    acc[i][j] = fmaf(av2[i], bv2[j], acc[i][j]);
        }
        __syncthreads();
    }
    unsigned long long (*red)[16] = (unsigned long long (*)[16])smem_raw;
    float cj[8];
    int   jglob[8];
    #pragma unroll
    for (int j = 0; j < 8; ++j) {
        int c = (j < 4) ? (tx*4 + j) : (64 + tx*4 + (j - 4));
        jglob[j] = bn + c;
        cj[j]    = psq[bn + c];
    }
    #pragma unroll
    for (int i = 0; i < 8; ++i) {
        float bestv = 0.f; unsigned bidx = 0u; bool first = true;
        #pragma unroll
        for (int j = 0; j < 8; ++j) {
            float s = fmaf(-2.f, acc[i][j], cj[j]);
            if (first || s < bestv) { bestv = s; bidx = (unsigned)jglob[j]; first = false; }
        }
        unsigned u = fkey(bestv);
        red[ty*8 + i][tx] = ((unsigned long long)u << 32) | (unsigned long long)bidx;
    }
    __syncthreads();
    if (tid < BM1) {
        unsigned long long m = red[tid][0];
        #pragma unroll
        for (int t = 1; t < 16; ++t) m = umin64(m, red[tid][t]);
        atomicMin(&minpack[bm + tid], m);
    }
}

__global__ void gather_kernel(const float* __restrict__ P,
                              const unsigned long long* __restrict__ minpack,
                              float* __restrict__ out) {
    int row = blockIdx.x;
    unsigned idx = (unsigned)(minpack[row] & 0xFFFFFFFFull);
    int lane = threadIdx.x;
    ((float4*)(out + (size_t)row * ND))[lane] =
        ((const float4*)(P + (size_t)idx * ND))[lane];
}

// ------------------------------------------------------------------- launch
extern "C" void kernel_launch(void* const* d_in, const int* in_sizes, int n_in,
                              void* d_out, int out_size, void* d_ws, size_t ws_size,
                              hipStream_t stream) {
    const float* X = (const float*)d_in[0];
    const float* P = (const float*)d_in[1];
    float* out = (float*)d_out;
    char* w = (char*)d_ws;

    if (ws_size >= WS_NEED) {
        float* psq = (float*)(w + OFF_PSQ);
        __bf16* Xb = (__bf16*)(w + OFF_XB);
        __bf16* Pb = (__bf16*)(w + OFF_PB);
        unsigned* blockmin = (unsigned*)(w + OFF_BM);

        prep_kernel<<<(NP + NB) / 4, 256, 0, stream>>>(X, P, psq, Xb, Pb);
        nn_dpp_kernel<<<(NB / 128) * NSPLIT, 512, 0, stream>>>(Xb, Pb, psq,
                                                               blockmin);
        rescore_wave_kernel<<<NB / 8, 512, 0, stream>>>(X, P, psq, blockmin, out);
    } else {
        float* psq = (float*)w;
        unsigned long long* minpack = (unsigned long long*)(w + (size_t)NP * 4);
        psq_init_kernel<<<NP / 4, 256, 0, stream>>>(P, psq, minpack);
        dim3 grid(NP / BN1, NB / BM1);
        nn_main_kernel<<<grid, dim3(256), 0, stream>>>(X, P, psq, minpack);
        gather_kernel<<<NB, 64, 0, stream>>>(P, minpack, out);
    }
}